// Round 1
// baseline (3083.537 us; speedup 1.0000x reference)
//
#include <hip/hip_runtime.h>
#include <math.h>

#define NN 100000
#define NE 1600000
#define INF 128
#define HID 256
#define BM 64

// ---- degree counting (float atomics; counts are small integers, exact) ----
__global__ void k_degrees(const int* __restrict__ src, const int* __restrict__ dst,
                          float* __restrict__ dout, float* __restrict__ din) {
    int e = blockIdx.x * blockDim.x + threadIdx.x;
    if (e < NE) {
        atomicAdd(&dout[src[e]], 1.0f);
        atomicAdd(&din[dst[e]], 1.0f);
    }
}

// ---- in-place: deg -> rsqrt(max(deg,1)) ----
__global__ void k_norms(float* __restrict__ dout, float* __restrict__ din) {
    int i = blockIdx.x * blockDim.x + threadIdx.x;
    if (i < NN) {
        dout[i] = rsqrtf(fmaxf(dout[i], 1.0f));
        din[i]  = rsqrtf(fmaxf(din[i], 1.0f));
    }
}

// ---- layer-1 message scatter: agg[dst] += x[src] * norm_out[src] ----
// 32 threads per edge, float4 per thread (128 feats).
__global__ void k_scatter1(const float* __restrict__ x, const int* __restrict__ src,
                           const int* __restrict__ dst, const float* __restrict__ nrm_out,
                           float* __restrict__ agg) {
    int tid = blockIdx.x * blockDim.x + threadIdx.x;
    int e = tid >> 5;
    if (e >= NE) return;
    int c = (tid & 31) << 2;
    int s = src[e], d = dst[e];
    float ns = nrm_out[s];
    float4 v = *reinterpret_cast<const float4*>(x + (size_t)s * INF + c);
    float* o = agg + (size_t)d * INF + c;
    atomicAdd(o + 0, v.x * ns);
    atomicAdd(o + 1, v.y * ns);
    atomicAdd(o + 2, v.z * ns);
    atomicAdd(o + 3, v.w * ns);
}

// ---- fused: z = norm_out * ( relu( (agg*norm_in) @ W1 + b1 ) @ W2 ) ----
// Block: 256 threads, 64 rows x 256 cols. Thread (rg=t>>5, cg=t&31) owns
// 8 rows (rg*8..) x 8 cols {cg*4+0..3, 128+cg*4+0..3}. A staged in LDS
// [64][136] (pad -> conflict-free b128 reads across k), W1 staged in 4
// chunks of [32][256]. h1 never materialized: epilogue does relu+W2-dot
// and a 32-lane shfl reduction.
__launch_bounds__(256, 2)
__global__ void k_gemm_fused(const float* __restrict__ agg, const float* __restrict__ nrm_in,
                             const float* __restrict__ nrm_out,
                             const float* __restrict__ W1, const float* __restrict__ b1,
                             const float* __restrict__ W2, float* __restrict__ z) {
    __shared__ float A[BM][136];
    __shared__ float Wc[32][256];

    const int t = threadIdx.x;
    const int cg = t & 31;
    const int rg = t >> 5;
    const int r0 = blockIdx.x * BM;

    // stage A (with norm_in folded), conflict-free float4 writes
    for (int c = t; c < BM * 32; c += 256) {
        int row = c >> 5, k4 = (c & 31) << 2;
        int gr = r0 + row;
        float4 v = make_float4(0.f, 0.f, 0.f, 0.f);
        float ni = 0.f;
        if (gr < NN) {
            v = *reinterpret_cast<const float4*>(agg + (size_t)gr * INF + k4);
            ni = nrm_in[gr];
        }
        float4 w = make_float4(v.x * ni, v.y * ni, v.z * ni, v.w * ni);
        *reinterpret_cast<float4*>(&A[row][k4]) = w;
    }

    float acc[8][8];
    #pragma unroll
    for (int i = 0; i < 8; ++i)
        #pragma unroll
        for (int j = 0; j < 8; ++j) acc[i][j] = 0.f;

    for (int kc = 0; kc < 4; ++kc) {
        __syncthreads();   // protect Wc from previous chunk / finish A staging
        for (int c = t; c < 32 * 64; c += 256) {
            int kk = c >> 6, cc = (c & 63) << 2;
            *reinterpret_cast<float4*>(&Wc[kk][cc]) =
                *reinterpret_cast<const float4*>(W1 + (size_t)(kc * 32 + kk) * HID + cc);
        }
        __syncthreads();

        #pragma unroll
        for (int k = 0; k < 32; k += 4) {
            float4 av[8];
            #pragma unroll
            for (int i = 0; i < 8; ++i)
                av[i] = *reinterpret_cast<const float4*>(&A[rg * 8 + i][kc * 32 + k]);
            #pragma unroll
            for (int kk = 0; kk < 4; ++kk) {
                float4 wa = *reinterpret_cast<const float4*>(&Wc[k + kk][cg * 4]);
                float4 wb = *reinterpret_cast<const float4*>(&Wc[k + kk][128 + cg * 4]);
                #pragma unroll
                for (int i = 0; i < 8; ++i) {
                    float a = (&av[i].x)[kk];
                    acc[i][0] = fmaf(a, wa.x, acc[i][0]);
                    acc[i][1] = fmaf(a, wa.y, acc[i][1]);
                    acc[i][2] = fmaf(a, wa.z, acc[i][2]);
                    acc[i][3] = fmaf(a, wa.w, acc[i][3]);
                    acc[i][4] = fmaf(a, wb.x, acc[i][4]);
                    acc[i][5] = fmaf(a, wb.y, acc[i][5]);
                    acc[i][6] = fmaf(a, wb.z, acc[i][6]);
                    acc[i][7] = fmaf(a, wb.w, acc[i][7]);
                }
            }
        }
    }

    // epilogue: relu + b1, dot with W2, reduce across 32 col-group lanes
    const int c0 = cg * 4, c1 = 128 + cg * 4;
    float4 b1a = *reinterpret_cast<const float4*>(b1 + c0);
    float4 b1b = *reinterpret_cast<const float4*>(b1 + c1);
    float4 w2a = *reinterpret_cast<const float4*>(W2 + c0);
    float4 w2b = *reinterpret_cast<const float4*>(W2 + c1);

    float p[8];
    #pragma unroll
    for (int i = 0; i < 8; ++i) {
        float s = 0.f;
        s += fmaxf(acc[i][0] + b1a.x, 0.f) * w2a.x;
        s += fmaxf(acc[i][1] + b1a.y, 0.f) * w2a.y;
        s += fmaxf(acc[i][2] + b1a.z, 0.f) * w2a.z;
        s += fmaxf(acc[i][3] + b1a.w, 0.f) * w2a.w;
        s += fmaxf(acc[i][4] + b1b.x, 0.f) * w2b.x;
        s += fmaxf(acc[i][5] + b1b.y, 0.f) * w2b.y;
        s += fmaxf(acc[i][6] + b1b.z, 0.f) * w2b.z;
        s += fmaxf(acc[i][7] + b1b.w, 0.f) * w2b.w;
        p[i] = s;
    }
    #pragma unroll
    for (int off = 16; off >= 1; off >>= 1) {
        #pragma unroll
        for (int i = 0; i < 8; ++i) p[i] += __shfl_xor(p[i], off, 64);
    }
    if (cg == 0) {
        #pragma unroll
        for (int i = 0; i < 8; ++i) {
            int gr = r0 + rg * 8 + i;
            if (gr < NN) z[gr] = nrm_out[gr] * p[i];
        }
    }
}

// ---- layer-2 scalar scatter: out[dst] += z[src] ----
__global__ void k_scatter2(const float* __restrict__ z, const int* __restrict__ src,
                           const int* __restrict__ dst, float* __restrict__ out) {
    int e = blockIdx.x * blockDim.x + threadIdx.x;
    if (e < NE) atomicAdd(&out[dst[e]], z[src[e]]);
}

// ---- finalize: out = sigmoid(out * norm_in + b2) ----
__global__ void k_final(float* __restrict__ out, const float* __restrict__ nrm_in,
                        const float* __restrict__ b2) {
    int i = blockIdx.x * blockDim.x + threadIdx.x;
    if (i < NN) {
        float v = out[i] * nrm_in[i] + b2[0];
        out[i] = 1.0f / (1.0f + expf(-v));
    }
}

extern "C" void kernel_launch(void* const* d_in, const int* in_sizes, int n_in,
                              void* d_out, int out_size, void* d_ws, size_t ws_size,
                              hipStream_t stream) {
    const float* x   = (const float*)d_in[0];
    const int*   src = (const int*)d_in[1];
    const int*   dst = (const int*)d_in[2];
    const float* W1  = (const float*)d_in[3];
    const float* b1  = (const float*)d_in[4];
    const float* W2  = (const float*)d_in[5];
    const float* b2  = (const float*)d_in[6];
    float* out = (float*)d_out;

    float* nrm_out = (float*)d_ws;                 // NN
    float* nrm_in  = nrm_out + NN;                 // NN
    float* agg     = nrm_in + NN;                  // NN*128
    float* z       = agg + (size_t)NN * INF;       // NN

    hipMemsetAsync(nrm_out, 0, 2 * NN * sizeof(float), stream);
    hipMemsetAsync(agg, 0, (size_t)NN * INF * sizeof(float), stream);
    hipMemsetAsync(d_out, 0, NN * sizeof(float), stream);

    k_degrees<<<(NE + 255) / 256, 256, 0, stream>>>(src, dst, nrm_out, nrm_in);
    k_norms<<<(NN + 255) / 256, 256, 0, stream>>>(nrm_out, nrm_in);
    k_scatter1<<<(NE * 32) / 256, 256, 0, stream>>>(x, src, dst, nrm_out, agg);
    k_gemm_fused<<<(NN + BM - 1) / BM, 256, 0, stream>>>(agg, nrm_in, nrm_out, W1, b1, W2, z);
    k_scatter2<<<(NE + 255) / 256, 256, 0, stream>>>(z, src, dst, out);
    k_final<<<(NN + 255) / 256, 256, 0, stream>>>(out, nrm_in, b2);
}

// Round 2
// 689.905 us; speedup vs baseline: 4.4695x; 4.4695x over previous
//
#include <hip/hip_runtime.h>
#include <math.h>

#define NN 100000
#define NE 1600000
#define INF 128
#define HID 256
#define BM 64
#define SCAN_BLK 256
#define NSCAN ((NN + SCAN_BLK - 1) / SCAN_BLK)   // 391

// ---- degree counting (int atomics) ----
__global__ void k_count(const int* __restrict__ src, const int* __restrict__ dst,
                        int* __restrict__ deg_out, int* __restrict__ deg_in) {
    int e = blockIdx.x * blockDim.x + threadIdx.x;
    if (e < NE) {
        atomicAdd(&deg_out[src[e]], 1);
        atomicAdd(&deg_in[dst[e]], 1);
    }
}

// ---- norms from int degrees ----
__global__ void k_norms(const int* __restrict__ deg_out, const int* __restrict__ deg_in,
                        float* __restrict__ nrm_out, float* __restrict__ nrm_in) {
    int i = blockIdx.x * blockDim.x + threadIdx.x;
    if (i < NN) {
        nrm_out[i] = rsqrtf(fmaxf((float)deg_out[i], 1.0f));
        nrm_in[i]  = rsqrtf(fmaxf((float)deg_in[i], 1.0f));
    }
}

// ---- scan phase 1: per-block sums of deg_in ----
__global__ void k_scan1(const int* __restrict__ deg_in, int* __restrict__ partial) {
    __shared__ int sh[SCAN_BLK];
    int i = blockIdx.x * SCAN_BLK + threadIdx.x;
    int v = (i < NN) ? deg_in[i] : 0;
    sh[threadIdx.x] = v;
    __syncthreads();
    for (int off = SCAN_BLK / 2; off > 0; off >>= 1) {
        if (threadIdx.x < off) sh[threadIdx.x] += sh[threadIdx.x + off];
        __syncthreads();
    }
    if (threadIdx.x == 0) partial[blockIdx.x] = sh[0];
}

// ---- scan phase 2: serial exclusive scan of 391 partials (trivial) ----
__global__ void k_scan2(int* __restrict__ partial) {
    if (threadIdx.x == 0 && blockIdx.x == 0) {
        int running = 0;
        for (int b = 0; b < NSCAN; ++b) {
            int t = partial[b];
            partial[b] = running;
            running += t;
        }
    }
}

// ---- scan phase 3: in-block exclusive scan + partial offset -> offsets, cursor ----
__global__ void k_scan3(const int* __restrict__ deg_in, const int* __restrict__ partial,
                        int* __restrict__ offsets, int* __restrict__ cursor) {
    __shared__ int sh[SCAN_BLK];
    int i = blockIdx.x * SCAN_BLK + threadIdx.x;
    int v = (i < NN) ? deg_in[i] : 0;
    sh[threadIdx.x] = v;
    __syncthreads();
    // Hillis-Steele inclusive scan
    for (int off = 1; off < SCAN_BLK; off <<= 1) {
        int t = (threadIdx.x >= off) ? sh[threadIdx.x - off] : 0;
        __syncthreads();
        sh[threadIdx.x] += t;
        __syncthreads();
    }
    int ex = sh[threadIdx.x] - v + partial[blockIdx.x];
    if (i < NN) {
        offsets[i] = ex;
        cursor[i] = ex;
    }
    if (i == 0) offsets[NN] = NE;
}

// ---- CSR fill: bucket edges by dst (order within bucket arbitrary) ----
__global__ void k_fill(const int* __restrict__ src, const int* __restrict__ dst,
                       int* __restrict__ cursor, int* __restrict__ csr_src) {
    int e = blockIdx.x * blockDim.x + threadIdx.x;
    if (e < NE) {
        int p = atomicAdd(&cursor[dst[e]], 1);
        csr_src[p] = src[e];
    }
}

// ---- fused: gather-aggregate -> A tile -> GEMM(W1) -> relu -> dot(W2) -> z ----
// z[v] = nrm_out[v] * ( relu( (nrm_in[v] * sum_{e: dst=v} x[src]*nrm_out[src]) @ W1 + b1 ) @ W2 )
__launch_bounds__(256, 2)
__global__ void k_gemm_fused(const float* __restrict__ x, const int* __restrict__ offsets,
                             const int* __restrict__ csr_src,
                             const float* __restrict__ nrm_in, const float* __restrict__ nrm_out,
                             const float* __restrict__ W1, const float* __restrict__ b1,
                             const float* __restrict__ W2, float* __restrict__ z) {
    __shared__ float A[BM][136];
    __shared__ float Wc[32][256];

    const int t = threadIdx.x;
    const int cg = t & 31;
    const int rg = t >> 5;
    const int r0 = blockIdx.x * BM;

    // stage A via CSR gather: 8 groups of 32 lanes, each group owns rows rg, rg+8, ...
    for (int rr = rg; rr < BM; rr += 8) {
        int gr = r0 + rr;
        float4 acc = make_float4(0.f, 0.f, 0.f, 0.f);
        if (gr < NN) {
            int beg = offsets[gr], end = offsets[gr + 1];
            float ni = nrm_in[gr];
            for (int j = beg; j < end; ++j) {
                int s = csr_src[j];
                float ns = nrm_out[s];
                float4 v = *reinterpret_cast<const float4*>(x + (size_t)s * INF + (cg << 2));
                acc.x = fmaf(v.x, ns, acc.x);
                acc.y = fmaf(v.y, ns, acc.y);
                acc.z = fmaf(v.z, ns, acc.z);
                acc.w = fmaf(v.w, ns, acc.w);
            }
            acc.x *= ni; acc.y *= ni; acc.z *= ni; acc.w *= ni;
        }
        *reinterpret_cast<float4*>(&A[rr][cg << 2]) = acc;
    }

    float acc[8][8];
    #pragma unroll
    for (int i = 0; i < 8; ++i)
        #pragma unroll
        for (int j = 0; j < 8; ++j) acc[i][j] = 0.f;

    for (int kc = 0; kc < 4; ++kc) {
        __syncthreads();   // A complete (first iter) / Wc consumed (later iters)
        for (int c = t; c < 32 * 64; c += 256) {
            int kk = c >> 6, cc = (c & 63) << 2;
            *reinterpret_cast<float4*>(&Wc[kk][cc]) =
                *reinterpret_cast<const float4*>(W1 + (size_t)(kc * 32 + kk) * HID + cc);
        }
        __syncthreads();

        #pragma unroll
        for (int k = 0; k < 32; k += 4) {
            float4 av[8];
            #pragma unroll
            for (int i = 0; i < 8; ++i)
                av[i] = *reinterpret_cast<const float4*>(&A[rg * 8 + i][kc * 32 + k]);
            #pragma unroll
            for (int kk = 0; kk < 4; ++kk) {
                float4 wa = *reinterpret_cast<const float4*>(&Wc[k + kk][cg * 4]);
                float4 wb = *reinterpret_cast<const float4*>(&Wc[k + kk][128 + cg * 4]);
                #pragma unroll
                for (int i = 0; i < 8; ++i) {
                    float a = (&av[i].x)[kk];
                    acc[i][0] = fmaf(a, wa.x, acc[i][0]);
                    acc[i][1] = fmaf(a, wa.y, acc[i][1]);
                    acc[i][2] = fmaf(a, wa.z, acc[i][2]);
                    acc[i][3] = fmaf(a, wa.w, acc[i][3]);
                    acc[i][4] = fmaf(a, wb.x, acc[i][4]);
                    acc[i][5] = fmaf(a, wb.y, acc[i][5]);
                    acc[i][6] = fmaf(a, wb.z, acc[i][6]);
                    acc[i][7] = fmaf(a, wb.w, acc[i][7]);
                }
            }
        }
    }

    // epilogue: relu + b1, dot with W2, reduce across 32 col-group lanes
    const int c0 = cg * 4, c1 = 128 + cg * 4;
    float4 b1a = *reinterpret_cast<const float4*>(b1 + c0);
    float4 b1b = *reinterpret_cast<const float4*>(b1 + c1);
    float4 w2a = *reinterpret_cast<const float4*>(W2 + c0);
    float4 w2b = *reinterpret_cast<const float4*>(W2 + c1);

    float p[8];
    #pragma unroll
    for (int i = 0; i < 8; ++i) {
        float s = 0.f;
        s += fmaxf(acc[i][0] + b1a.x, 0.f) * w2a.x;
        s += fmaxf(acc[i][1] + b1a.y, 0.f) * w2a.y;
        s += fmaxf(acc[i][2] + b1a.z, 0.f) * w2a.z;
        s += fmaxf(acc[i][3] + b1a.w, 0.f) * w2a.w;
        s += fmaxf(acc[i][4] + b1b.x, 0.f) * w2b.x;
        s += fmaxf(acc[i][5] + b1b.y, 0.f) * w2b.y;
        s += fmaxf(acc[i][6] + b1b.z, 0.f) * w2b.z;
        s += fmaxf(acc[i][7] + b1b.w, 0.f) * w2b.w;
        p[i] = s;
    }
    #pragma unroll
    for (int off = 16; off >= 1; off >>= 1) {
        #pragma unroll
        for (int i = 0; i < 8; ++i) p[i] += __shfl_xor(p[i], off, 64);
    }
    if (cg == 0) {
        #pragma unroll
        for (int i = 0; i < 8; ++i) {
            int gr = r0 + rg * 8 + i;
            if (gr < NN) z[gr] = nrm_out[gr] * p[i];
        }
    }
}

// ---- layer-2 gather + sigmoid: out[v] = sigmoid(nrm_in[v]*sum z[csr_src] + b2) ----
__global__ void k_out(const float* __restrict__ z, const int* __restrict__ offsets,
                      const int* __restrict__ csr_src, const float* __restrict__ nrm_in,
                      const float* __restrict__ b2, float* __restrict__ out) {
    int v = blockIdx.x * blockDim.x + threadIdx.x;
    if (v < NN) {
        float s = 0.f;
        int beg = offsets[v], end = offsets[v + 1];
        for (int j = beg; j < end; ++j) s += z[csr_src[j]];
        float val = s * nrm_in[v] + b2[0];
        out[v] = 1.0f / (1.0f + expf(-val));
    }
}

extern "C" void kernel_launch(void* const* d_in, const int* in_sizes, int n_in,
                              void* d_out, int out_size, void* d_ws, size_t ws_size,
                              hipStream_t stream) {
    const float* x   = (const float*)d_in[0];
    const int*   src = (const int*)d_in[1];
    const int*   dst = (const int*)d_in[2];
    const float* W1  = (const float*)d_in[3];
    const float* b1  = (const float*)d_in[4];
    const float* W2  = (const float*)d_in[5];
    const float* b2  = (const float*)d_in[6];
    float* out = (float*)d_out;

    // workspace layout (all 4-byte aligned)
    int*   deg_out = (int*)d_ws;                     // NN
    int*   deg_in  = deg_out + NN;                   // NN
    int*   offsets = deg_in + NN;                    // NN+1
    int*   cursor  = offsets + NN + 1;               // NN
    int*   partial = cursor + NN;                    // NSCAN
    int*   csr_src = partial + NSCAN;                // NE
    float* nrm_out = (float*)(csr_src + NE);         // NN
    float* nrm_in  = nrm_out + NN;                   // NN
    float* z       = nrm_in + NN;                    // NN

    hipMemsetAsync(deg_out, 0, 2 * NN * sizeof(int), stream);

    k_count<<<(NE + 255) / 256, 256, 0, stream>>>(src, dst, deg_out, deg_in);
    k_norms<<<(NN + 255) / 256, 256, 0, stream>>>(deg_out, deg_in, nrm_out, nrm_in);
    k_scan1<<<NSCAN, SCAN_BLK, 0, stream>>>(deg_in, partial);
    k_scan2<<<1, 64, 0, stream>>>(partial);
    k_scan3<<<NSCAN, SCAN_BLK, 0, stream>>>(deg_in, partial, offsets, cursor);
    k_fill<<<(NE + 255) / 256, 256, 0, stream>>>(src, dst, cursor, csr_src);
    k_gemm_fused<<<(NN + BM - 1) / BM, 256, 0, stream>>>(x, offsets, csr_src, nrm_in, nrm_out,
                                                         W1, b1, W2, z);
    k_out<<<(NN + 255) / 256, 256, 0, stream>>>(z, offsets, csr_src, nrm_in, b2, out);
}

// Round 3
// 509.170 us; speedup vs baseline: 6.0560x; 1.3550x over previous
//
#include <hip/hip_runtime.h>
#include <math.h>

#define NN 100000
#define NE 1600000
#define INF 128
#define HID 256
#define BM 64
#define SCAN_BLK 256
#define NSCAN ((NN + SCAN_BLK - 1) / SCAN_BLK)   // 391

// ---- degree counting (int atomics) ----
__global__ void k_count(const int* __restrict__ src, const int* __restrict__ dst,
                        int* __restrict__ deg_out, int* __restrict__ deg_in) {
    int e = blockIdx.x * blockDim.x + threadIdx.x;
    if (e < NE) {
        atomicAdd(&deg_out[src[e]], 1);
        atomicAdd(&deg_in[dst[e]], 1);
    }
}

// ---- norms from int degrees ----
__global__ void k_norms(const int* __restrict__ deg_out, const int* __restrict__ deg_in,
                        float* __restrict__ nrm_out, float* __restrict__ nrm_in) {
    int i = blockIdx.x * blockDim.x + threadIdx.x;
    if (i < NN) {
        nrm_out[i] = rsqrtf(fmaxf((float)deg_out[i], 1.0f));
        nrm_in[i]  = rsqrtf(fmaxf((float)deg_in[i], 1.0f));
    }
}

// ---- scan phase 1: per-block sums of deg_in ----
__global__ void k_scan1(const int* __restrict__ deg_in, int* __restrict__ partial) {
    __shared__ int sh[SCAN_BLK];
    int i = blockIdx.x * SCAN_BLK + threadIdx.x;
    int v = (i < NN) ? deg_in[i] : 0;
    sh[threadIdx.x] = v;
    __syncthreads();
    for (int off = SCAN_BLK / 2; off > 0; off >>= 1) {
        if (threadIdx.x < off) sh[threadIdx.x] += sh[threadIdx.x + off];
        __syncthreads();
    }
    if (threadIdx.x == 0) partial[blockIdx.x] = sh[0];
}

// ---- scan phase 2: serial exclusive scan of 391 partials ----
__global__ void k_scan2(int* __restrict__ partial) {
    if (threadIdx.x == 0 && blockIdx.x == 0) {
        int running = 0;
        for (int b = 0; b < NSCAN; ++b) {
            int t = partial[b];
            partial[b] = running;
            running += t;
        }
    }
}

// ---- scan phase 3: in-block exclusive scan + block offset -> offsets, cursor ----
__global__ void k_scan3(const int* __restrict__ deg_in, const int* __restrict__ partial,
                        int* __restrict__ offsets, int* __restrict__ cursor) {
    __shared__ int sh[SCAN_BLK];
    int i = blockIdx.x * SCAN_BLK + threadIdx.x;
    int v = (i < NN) ? deg_in[i] : 0;
    sh[threadIdx.x] = v;
    __syncthreads();
    for (int off = 1; off < SCAN_BLK; off <<= 1) {
        int t = (threadIdx.x >= off) ? sh[threadIdx.x - off] : 0;
        __syncthreads();
        sh[threadIdx.x] += t;
        __syncthreads();
    }
    int ex = sh[threadIdx.x] - v + partial[blockIdx.x];
    if (i < NN) {
        offsets[i] = ex;
        cursor[i] = ex;
    }
    if (i == 0) offsets[NN] = NE;
}

// ---- CSR fill: bucket edges by dst ----
__global__ void k_fill(const int* __restrict__ src, const int* __restrict__ dst,
                       int* __restrict__ cursor, int* __restrict__ csr_src) {
    int e = blockIdx.x * blockDim.x + threadIdx.x;
    if (e < NE) {
        int p = atomicAdd(&cursor[dst[e]], 1);
        csr_src[p] = src[e];
    }
}

// ---- gather-aggregate: agg[v] = nrm_in[v] * sum_{e:dst=v} x[src]*nrm_out[src] ----
// 32 lanes per row, float4/lane, no LDS, tiny VGPR -> max occupancy.
__global__ void k_gather(const float* __restrict__ x, const int* __restrict__ offsets,
                         const int* __restrict__ csr_src, const float* __restrict__ nrm_in,
                         const float* __restrict__ nrm_out, float* __restrict__ agg) {
    int g = (blockIdx.x * blockDim.x + threadIdx.x) >> 5;
    if (g >= NN) return;
    int c = (threadIdx.x & 31) << 2;
    int beg = offsets[g], end = offsets[g + 1];
    float ni = nrm_in[g];
    float4 a0 = make_float4(0.f, 0.f, 0.f, 0.f);
    float4 a1 = make_float4(0.f, 0.f, 0.f, 0.f);
    int j = beg;
    for (; j + 1 < end; j += 2) {
        int s0 = csr_src[j], s1 = csr_src[j + 1];
        float n0 = nrm_out[s0], n1 = nrm_out[s1];
        float4 v0 = *reinterpret_cast<const float4*>(x + (size_t)s0 * INF + c);
        float4 v1 = *reinterpret_cast<const float4*>(x + (size_t)s1 * INF + c);
        a0.x = fmaf(v0.x, n0, a0.x); a0.y = fmaf(v0.y, n0, a0.y);
        a0.z = fmaf(v0.z, n0, a0.z); a0.w = fmaf(v0.w, n0, a0.w);
        a1.x = fmaf(v1.x, n1, a1.x); a1.y = fmaf(v1.y, n1, a1.y);
        a1.z = fmaf(v1.z, n1, a1.z); a1.w = fmaf(v1.w, n1, a1.w);
    }
    if (j < end) {
        int s0 = csr_src[j];
        float n0 = nrm_out[s0];
        float4 v0 = *reinterpret_cast<const float4*>(x + (size_t)s0 * INF + c);
        a0.x = fmaf(v0.x, n0, a0.x); a0.y = fmaf(v0.y, n0, a0.y);
        a0.z = fmaf(v0.z, n0, a0.z); a0.w = fmaf(v0.w, n0, a0.w);
    }
    float4 r;
    r.x = (a0.x + a1.x) * ni; r.y = (a0.y + a1.y) * ni;
    r.z = (a0.z + a1.z) * ni; r.w = (a0.w + a1.w) * ni;
    *reinterpret_cast<float4*>(agg + (size_t)g * INF + c) = r;
}

// ---- GEMM(W1) + relu + dot(W2) -> z.  A-staging is a coalesced copy. ----
__launch_bounds__(256, 2)
__global__ void k_gemm(const float* __restrict__ agg,
                       const float* __restrict__ nrm_out,
                       const float* __restrict__ W1, const float* __restrict__ b1,
                       const float* __restrict__ W2, float* __restrict__ z) {
    __shared__ float A[BM][136];
    __shared__ float Wc[32][256];

    const int t = threadIdx.x;
    const int cg = t & 31;
    const int rg = t >> 5;
    const int r0 = blockIdx.x * BM;

    for (int c = t; c < BM * 32; c += 256) {
        int row = c >> 5, k4 = (c & 31) << 2;
        int gr = r0 + row;
        float4 v = make_float4(0.f, 0.f, 0.f, 0.f);
        if (gr < NN) v = *reinterpret_cast<const float4*>(agg + (size_t)gr * INF + k4);
        *reinterpret_cast<float4*>(&A[row][k4]) = v;
    }

    float acc[8][8];
    #pragma unroll
    for (int i = 0; i < 8; ++i)
        #pragma unroll
        for (int j = 0; j < 8; ++j) acc[i][j] = 0.f;

    for (int kc = 0; kc < 4; ++kc) {
        __syncthreads();
        for (int c = t; c < 32 * 64; c += 256) {
            int kk = c >> 6, cc = (c & 63) << 2;
            *reinterpret_cast<float4*>(&Wc[kk][cc]) =
                *reinterpret_cast<const float4*>(W1 + (size_t)(kc * 32 + kk) * HID + cc);
        }
        __syncthreads();

        #pragma unroll
        for (int k = 0; k < 32; k += 4) {
            float4 av[8];
            #pragma unroll
            for (int i = 0; i < 8; ++i)
                av[i] = *reinterpret_cast<const float4*>(&A[rg * 8 + i][kc * 32 + k]);
            #pragma unroll
            for (int kk = 0; kk < 4; ++kk) {
                float4 wa = *reinterpret_cast<const float4*>(&Wc[k + kk][cg * 4]);
                float4 wb = *reinterpret_cast<const float4*>(&Wc[k + kk][128 + cg * 4]);
                #pragma unroll
                for (int i = 0; i < 8; ++i) {
                    float a = (&av[i].x)[kk];
                    acc[i][0] = fmaf(a, wa.x, acc[i][0]);
                    acc[i][1] = fmaf(a, wa.y, acc[i][1]);
                    acc[i][2] = fmaf(a, wa.z, acc[i][2]);
                    acc[i][3] = fmaf(a, wa.w, acc[i][3]);
                    acc[i][4] = fmaf(a, wb.x, acc[i][4]);
                    acc[i][5] = fmaf(a, wb.y, acc[i][5]);
                    acc[i][6] = fmaf(a, wb.z, acc[i][6]);
                    acc[i][7] = fmaf(a, wb.w, acc[i][7]);
                }
            }
        }
    }

    const int c0 = cg * 4, c1 = 128 + cg * 4;
    float4 b1a = *reinterpret_cast<const float4*>(b1 + c0);
    float4 b1b = *reinterpret_cast<const float4*>(b1 + c1);
    float4 w2a = *reinterpret_cast<const float4*>(W2 + c0);
    float4 w2b = *reinterpret_cast<const float4*>(W2 + c1);

    float p[8];
    #pragma unroll
    for (int i = 0; i < 8; ++i) {
        float s = 0.f;
        s += fmaxf(acc[i][0] + b1a.x, 0.f) * w2a.x;
        s += fmaxf(acc[i][1] + b1a.y, 0.f) * w2a.y;
        s += fmaxf(acc[i][2] + b1a.z, 0.f) * w2a.z;
        s += fmaxf(acc[i][3] + b1a.w, 0.f) * w2a.w;
        s += fmaxf(acc[i][4] + b1b.x, 0.f) * w2b.x;
        s += fmaxf(acc[i][5] + b1b.y, 0.f) * w2b.y;
        s += fmaxf(acc[i][6] + b1b.z, 0.f) * w2b.z;
        s += fmaxf(acc[i][7] + b1b.w, 0.f) * w2b.w;
        p[i] = s;
    }
    #pragma unroll
    for (int off = 16; off >= 1; off >>= 1) {
        #pragma unroll
        for (int i = 0; i < 8; ++i) p[i] += __shfl_xor(p[i], off, 64);
    }
    if (cg == 0) {
        #pragma unroll
        for (int i = 0; i < 8; ++i) {
            int gr = r0 + rg * 8 + i;
            if (gr < NN) z[gr] = nrm_out[gr] * p[i];
        }
    }
}

// ---- layer-2 gather + sigmoid ----
__global__ void k_out(const float* __restrict__ z, const int* __restrict__ offsets,
                      const int* __restrict__ csr_src, const float* __restrict__ nrm_in,
                      const float* __restrict__ b2, float* __restrict__ out) {
    int v = blockIdx.x * blockDim.x + threadIdx.x;
    if (v < NN) {
        float s = 0.f;
        int beg = offsets[v], end = offsets[v + 1];
        for (int j = beg; j < end; ++j) s += z[csr_src[j]];
        float val = s * nrm_in[v] + b2[0];
        out[v] = 1.0f / (1.0f + expf(-val));
    }
}

extern "C" void kernel_launch(void* const* d_in, const int* in_sizes, int n_in,
                              void* d_out, int out_size, void* d_ws, size_t ws_size,
                              hipStream_t stream) {
    const float* x   = (const float*)d_in[0];
    const int*   src = (const int*)d_in[1];
    const int*   dst = (const int*)d_in[2];
    const float* W1  = (const float*)d_in[3];
    const float* b1  = (const float*)d_in[4];
    const float* W2  = (const float*)d_in[5];
    const float* b2  = (const float*)d_in[6];
    float* out = (float*)d_out;

    int*   deg_out = (int*)d_ws;                     // NN
    int*   deg_in  = deg_out + NN;                   // NN
    int*   offsets = deg_in + NN;                    // NN+1
    int*   cursor  = offsets + NN + 1;               // NN
    int*   partial = cursor + NN;                    // NSCAN
    int*   csr_src = partial + NSCAN;                // NE
    float* nrm_out = (float*)(csr_src + NE);         // NN
    float* nrm_in  = nrm_out + NN;                   // NN
    float* z       = nrm_in + NN;                    // NN
    float* agg     = z + NN;                         // NN*128

    hipMemsetAsync(deg_out, 0, 2 * NN * sizeof(int), stream);

    k_count<<<(NE + 255) / 256, 256, 0, stream>>>(src, dst, deg_out, deg_in);
    k_norms<<<(NN + 255) / 256, 256, 0, stream>>>(deg_out, deg_in, nrm_out, nrm_in);
    k_scan1<<<NSCAN, SCAN_BLK, 0, stream>>>(deg_in, partial);
    k_scan2<<<1, 64, 0, stream>>>(partial);
    k_scan3<<<NSCAN, SCAN_BLK, 0, stream>>>(deg_in, partial, offsets, cursor);
    k_fill<<<(NE + 255) / 256, 256, 0, stream>>>(src, dst, cursor, csr_src);
    k_gather<<<(NN * 32 + 255) / 256, 256, 0, stream>>>(x, offsets, csr_src, nrm_in, nrm_out, agg);
    k_gemm<<<(NN + BM - 1) / BM, 256, 0, stream>>>(agg, nrm_out, W1, b1, W2, z);
    k_out<<<(NN + 255) / 256, 256, 0, stream>>>(z, offsets, csr_src, nrm_in, b2, out);
}

// Round 5
// 424.446 us; speedup vs baseline: 7.2648x; 1.1996x over previous
//
#include <hip/hip_runtime.h>
#include <math.h>

#define NN 100000
#define NE 1600000
#define INF 128
#define HID 256
#define SCAN_BLK 256
#define NSCAN ((NN + SCAN_BLK - 1) / SCAN_BLK)   // 391

typedef short bf16x8 __attribute__((ext_vector_type(8)));
typedef float f32x4 __attribute__((ext_vector_type(4)));

__device__ __forceinline__ unsigned int f2bf(float f) {
    unsigned int u = __float_as_uint(f);
    u = u + 0x7FFFu + ((u >> 16) & 1u);   // RNE
    return u >> 16;
}

// ---- degree counting (int atomics) ----
__global__ void k_count(const int* __restrict__ src, const int* __restrict__ dst,
                        int* __restrict__ deg_out, int* __restrict__ deg_in) {
    int e = blockIdx.x * blockDim.x + threadIdx.x;
    if (e < NE) {
        atomicAdd(&deg_out[src[e]], 1);
        atomicAdd(&deg_in[dst[e]], 1);
    }
}

// ---- norms from int degrees ----
__global__ void k_norms(const int* __restrict__ deg_out, const int* __restrict__ deg_in,
                        float* __restrict__ nrm_out, float* __restrict__ nrm_in) {
    int i = blockIdx.x * blockDim.x + threadIdx.x;
    if (i < NN) {
        nrm_out[i] = rsqrtf(fmaxf((float)deg_out[i], 1.0f));
        nrm_in[i]  = rsqrtf(fmaxf((float)deg_in[i], 1.0f));
    }
}

// ---- xs = bf16(x * nrm_out[row]), packed 2/uint ----
__global__ void k_xconv(const float* __restrict__ x, const float* __restrict__ nrm_out,
                        unsigned int* __restrict__ xs) {
    int i = blockIdx.x * blockDim.x + threadIdx.x;   // one uint = 2 feats
    if (i >= NN * (INF / 2)) return;
    int row = i >> 6;                                 // 64 uints per row
    float n = nrm_out[row];
    float2 v = *reinterpret_cast<const float2*>(x + (size_t)i * 2);
    xs[i] = f2bf(v.x * n) | (f2bf(v.y * n) << 16);
}

// ---- W1 -> fragment-linear bf16 buffer + (b1,W2) pair table ----
// fragW[(nt*4+ks)*64 + l][i] = W1[ks*32 + (l>>4)*8 + i][nt*16 + (l&15)]
__global__ void k_wfrag(const float* __restrict__ W1, const float* __restrict__ b1,
                        const float* __restrict__ W2, unsigned short* __restrict__ fragW,
                        float2* __restrict__ bw) {
    int idx = blockIdx.x * blockDim.x + threadIdx.x;
    if (idx < 4096) {
        int l = idx & 63, ks = (idx >> 6) & 3, nt = idx >> 8;
        int kbase = ks * 32 + ((l >> 4) << 3);
        int col = nt * 16 + (l & 15);
        bf16x8 r;
        #pragma unroll
        for (int i = 0; i < 8; ++i)
            r[i] = (short)f2bf(W1[(size_t)(kbase + i) * HID + col]);
        *reinterpret_cast<bf16x8*>(fragW + (size_t)idx * 8) = r;
    } else if (idx < 4096 + HID) {
        int n = idx - 4096;
        bw[n] = make_float2(b1[n], W2[n]);
    }
}

// ---- scan phase 1: per-block sums of deg_in ----
__global__ void k_scan1(const int* __restrict__ deg_in, int* __restrict__ partial) {
    __shared__ int sh[SCAN_BLK];
    int i = blockIdx.x * SCAN_BLK + threadIdx.x;
    int v = (i < NN) ? deg_in[i] : 0;
    sh[threadIdx.x] = v;
    __syncthreads();
    for (int off = SCAN_BLK / 2; off > 0; off >>= 1) {
        if (threadIdx.x < off) sh[threadIdx.x] += sh[threadIdx.x + off];
        __syncthreads();
    }
    if (threadIdx.x == 0) partial[blockIdx.x] = sh[0];
}

// ---- scan phase 2: wave-parallel exclusive scan of 391 partials ----
__global__ void k_scan2(int* __restrict__ partial) {
    int lane = threadIdx.x;   // 64 threads, 1 block
    int carry = 0;
    for (int c = 0; c < NSCAN; c += 64) {
        int idx = c + lane;
        int v = (idx < NSCAN) ? partial[idx] : 0;
        int s = v;
        #pragma unroll
        for (int off = 1; off < 64; off <<= 1) {
            int t = __shfl_up(s, off, 64);
            if (lane >= off) s += t;
        }
        if (idx < NSCAN) partial[idx] = s - v + carry;
        carry += __shfl(s, 63, 64);
    }
}

// ---- scan phase 3: in-block exclusive scan + block offset -> offsets, cursor ----
__global__ void k_scan3(const int* __restrict__ deg_in, const int* __restrict__ partial,
                        int* __restrict__ offsets, int* __restrict__ cursor) {
    __shared__ int sh[SCAN_BLK];
    int i = blockIdx.x * SCAN_BLK + threadIdx.x;
    int v = (i < NN) ? deg_in[i] : 0;
    sh[threadIdx.x] = v;
    __syncthreads();
    for (int off = 1; off < SCAN_BLK; off <<= 1) {
        int t = (threadIdx.x >= off) ? sh[threadIdx.x - off] : 0;
        __syncthreads();
        sh[threadIdx.x] += t;
        __syncthreads();
    }
    int ex = sh[threadIdx.x] - v + partial[blockIdx.x];
    if (i < NN) {
        offsets[i] = ex;
        cursor[i] = ex;
    }
    if (i == 0) offsets[NN] = NE;
}

// ---- CSR fill: bucket edges by dst ----
__global__ void k_fill(const int* __restrict__ src, const int* __restrict__ dst,
                       int* __restrict__ cursor, int* __restrict__ csr_src) {
    int e = blockIdx.x * blockDim.x + threadIdx.x;
    if (e < NE) {
        int p = atomicAdd(&cursor[dst[e]], 1);
        csr_src[p] = src[e];
    }
}

// ---- gather: aggb[v] = bf16( nrm_in[v] * sum xs[src] ), one wave per row ----
__global__ void k_gather(const unsigned int* __restrict__ xs, const int* __restrict__ offsets,
                         const int* __restrict__ csr_src, const float* __restrict__ nrm_in,
                         unsigned int* __restrict__ aggb) {
    int row = blockIdx.x * 4 + (threadIdx.x >> 6);   // 4 waves/block, NN divisible by 4
    if (row >= NN) return;
    int lane = threadIdx.x & 63;
    int beg = offsets[row], end = offsets[row + 1];
    float a0 = 0.f, a1 = 0.f, b0 = 0.f, b1 = 0.f;
    int j = beg;
    for (; j + 1 < end; j += 2) {
        unsigned int p0 = xs[(size_t)csr_src[j] * 64 + lane];
        unsigned int p1 = xs[(size_t)csr_src[j + 1] * 64 + lane];
        a0 += __uint_as_float(p0 << 16);
        a1 += __uint_as_float(p0 & 0xFFFF0000u);
        b0 += __uint_as_float(p1 << 16);
        b1 += __uint_as_float(p1 & 0xFFFF0000u);
    }
    if (j < end) {
        unsigned int p0 = xs[(size_t)csr_src[j] * 64 + lane];
        a0 += __uint_as_float(p0 << 16);
        a1 += __uint_as_float(p0 & 0xFFFF0000u);
    }
    float ni = nrm_in[row];
    float lo = (a0 + b0) * ni, hi = (a1 + b1) * ni;
    aggb[(size_t)row * 64 + lane] = f2bf(lo) | (f2bf(hi) << 16);
}

// ---- MFMA GEMM (no LDS) + relu + W2-dot + shfl-reduce -> z ----
// wave w of 4 owns 16 rows; A-frags per-lane 16B global loads; B-frags from fragW.
__launch_bounds__(256)
__global__ void k_gemm(const unsigned short* __restrict__ aggb,
                       const unsigned short* __restrict__ fragW,
                       const float2* __restrict__ bw, const float* __restrict__ nrm_out,
                       float* __restrict__ z) {
    const int l = threadIdx.x & 63;
    const int w = threadIdx.x >> 6;
    const int r0 = blockIdx.x * 64 + w * 16;
    const int n15 = l & 15;
    const int hi = l >> 4;
    const int arow = r0 + n15;

    bf16x8 a[4];
    if (arow < NN) {
        #pragma unroll
        for (int ks = 0; ks < 4; ++ks)
            a[ks] = *reinterpret_cast<const bf16x8*>(aggb + (size_t)arow * INF + ks * 32 + (hi << 3));
    } else {
        #pragma unroll
        for (int ks = 0; ks < 4; ++ks) a[ks] = (bf16x8){0, 0, 0, 0, 0, 0, 0, 0};
    }

    float pacc[4] = {0.f, 0.f, 0.f, 0.f};
    #pragma unroll
    for (int nt = 0; nt < 16; ++nt) {
        f32x4 acc = {0.f, 0.f, 0.f, 0.f};
        #pragma unroll
        for (int ks = 0; ks < 4; ++ks) {
            bf16x8 b = *reinterpret_cast<const bf16x8*>(fragW + (size_t)(((nt * 4 + ks) * 64 + l) << 3));
            acc = __builtin_amdgcn_mfma_f32_16x16x32_bf16(a[ks], b, acc, 0, 0, 0);
        }
        float2 c = bw[nt * 16 + n15];
        #pragma unroll
        for (int g = 0; g < 4; ++g)
            pacc[g] += fmaxf(acc[g] + c.x, 0.f) * c.y;
    }
    #pragma unroll
    for (int off = 1; off < 16; off <<= 1) {
        #pragma unroll
        for (int g = 0; g < 4; ++g) pacc[g] += __shfl_xor(pacc[g], off, 64);
    }
    if (n15 == 0) {
        #pragma unroll
        for (int g = 0; g < 4; ++g) {
            int gr = r0 + (hi << 2) + g;   // D row = (l>>4)*4 + g
            if (gr < NN) z[gr] = nrm_out[gr] * pacc[g];
        }
    }
}

// ---- layer-2 gather + sigmoid ----
__global__ void k_out(const float* __restrict__ z, const int* __restrict__ offsets,
                      const int* __restrict__ csr_src, const float* __restrict__ nrm_in,
                      const float* __restrict__ b2, float* __restrict__ out) {
    int v = blockIdx.x * blockDim.x + threadIdx.x;
    if (v < NN) {
        float s = 0.f;
        int beg = offsets[v], end = offsets[v + 1];
        for (int j = beg; j < end; ++j) s += z[csr_src[j]];
        float val = s * nrm_in[v] + b2[0];
        out[v] = 1.0f / (1.0f + expf(-val));
    }
}

extern "C" void kernel_launch(void* const* d_in, const int* in_sizes, int n_in,
                              void* d_out, int out_size, void* d_ws, size_t ws_size,
                              hipStream_t stream) {
    const float* x   = (const float*)d_in[0];
    const int*   src = (const int*)d_in[1];
    const int*   dst = (const int*)d_in[2];
    const float* W1  = (const float*)d_in[3];
    const float* b1  = (const float*)d_in[4];
    const float* W2  = (const float*)d_in[5];
    const float* b2  = (const float*)d_in[6];
    float* out = (float*)d_out;

    // workspace layout (cursor aliases deg_out; all bf16 arrays 16B-aligned)
    int*   deg_out = (int*)d_ws;                     // NN   (later reused as cursor)
    int*   deg_in  = deg_out + NN;                   // NN
    int*   offsets = deg_in + NN;                    // NN+1
    int*   partial = offsets + NN + 1;               // NSCAN
    int*   csr_src = partial + NSCAN;                // NE
    float* nrm_out = (float*)(csr_src + NE);         // NN
    float* nrm_in  = nrm_out + NN;                   // NN
    float* z       = nrm_in + NN;                    // NN
    float2* bw     = (float2*)(z + NN);              // HID
    unsigned int* xs   = (unsigned int*)(bw + HID);  // NN*64  (25.6 MB)
    unsigned int* aggb = xs + (size_t)NN * 64;       // NN*64  (25.6 MB)
    unsigned short* fragW = (unsigned short*)(aggb + (size_t)NN * 64);  // 32768 (64 KB)
    int* cursor = deg_out;

    (void)hipMemsetAsync(deg_out, 0, 2 * NN * sizeof(int), stream);

    k_wfrag<<<17, 256, 0, stream>>>(W1, b1, W2, fragW, bw);
    k_count<<<(NE + 255) / 256, 256, 0, stream>>>(src, dst, deg_out, deg_in);
    k_norms<<<(NN + 255) / 256, 256, 0, stream>>>(deg_out, deg_in, nrm_out, nrm_in);
    k_xconv<<<(NN * 64 + 255) / 256, 256, 0, stream>>>(x, nrm_out, xs);
    k_scan1<<<NSCAN, SCAN_BLK, 0, stream>>>(deg_in, partial);
    k_scan2<<<1, 64, 0, stream>>>(partial);
    k_scan3<<<NSCAN, SCAN_BLK, 0, stream>>>(deg_in, partial, offsets, cursor);
    k_fill<<<(NE + 255) / 256, 256, 0, stream>>>(src, dst, cursor, csr_src);
    k_gather<<<NN / 4, 256, 0, stream>>>(xs, offsets, csr_src, nrm_in, aggb);
    k_gemm<<<(NN + 63) / 64, 256, 0, stream>>>((const unsigned short*)aggb, fragW, bw, nrm_out, z);
    k_out<<<(NN + 255) / 256, 256, 0, stream>>>(z, offsets, csr_src, nrm_in, b2, out);
}

// Round 6
// 369.637 us; speedup vs baseline: 8.3421x; 1.1483x over previous
//
#include <hip/hip_runtime.h>
#include <math.h>

#define NN 100000
#define NE 1600000
#define INF 128
#define HID 256
#define SCAN_BLK 256
#define NSCAN ((NN + SCAN_BLK - 1) / SCAN_BLK)   // 391
#define FGRP 8                    // dst-space partitions (≈ XCD count)
#define FRNG (NN / FGRP)          // 12500 dst per group
#define EPB 2048                  // edges scanned per virtual block
#define NVB ((NE + EPB - 1) / EPB)

typedef short bf16x8 __attribute__((ext_vector_type(8)));
typedef float f32x4 __attribute__((ext_vector_type(4)));

__device__ __forceinline__ unsigned int f2bf(float f) {
    unsigned int u = __float_as_uint(f);
    u = u + 0x7FFFu + ((u >> 16) & 1u);   // RNE
    return u >> 16;
}

// ---- degree counting (int atomics) ----
__global__ void k_count(const int* __restrict__ src, const int* __restrict__ dst,
                        int* __restrict__ deg_out, int* __restrict__ deg_in) {
    int e = blockIdx.x * blockDim.x + threadIdx.x;
    if (e < NE) {
        atomicAdd(&deg_out[src[e]], 1);
        atomicAdd(&deg_in[dst[e]], 1);
    }
}

// ---- norms from int degrees ----
__global__ void k_norms(const int* __restrict__ deg_out, const int* __restrict__ deg_in,
                        float* __restrict__ nrm_out, float* __restrict__ nrm_in) {
    int i = blockIdx.x * blockDim.x + threadIdx.x;
    if (i < NN) {
        nrm_out[i] = rsqrtf(fmaxf((float)deg_out[i], 1.0f));
        nrm_in[i]  = rsqrtf(fmaxf((float)deg_in[i], 1.0f));
    }
}

// ---- xs = bf16(x * nrm_out[row]), packed 2/uint ----
__global__ void k_xconv(const float* __restrict__ x, const float* __restrict__ nrm_out,
                        unsigned int* __restrict__ xs) {
    int i = blockIdx.x * blockDim.x + threadIdx.x;   // one uint = 2 feats
    if (i >= NN * (INF / 2)) return;
    int row = i >> 6;                                 // 64 uints per row
    float n = nrm_out[row];
    float2 v = *reinterpret_cast<const float2*>(x + (size_t)i * 2);
    xs[i] = f2bf(v.x * n) | (f2bf(v.y * n) << 16);
}

// ---- W1 -> fragment-linear bf16 buffer + (b1,W2) pair table ----
// fragW[(nt*4+ks)*64 + l][i] = W1[ks*32 + (l>>4)*8 + i][nt*16 + (l&15)]
__global__ void k_wfrag(const float* __restrict__ W1, const float* __restrict__ b1,
                        const float* __restrict__ W2, unsigned short* __restrict__ fragW,
                        float2* __restrict__ bw) {
    int idx = blockIdx.x * blockDim.x + threadIdx.x;
    if (idx < 4096) {
        int l = idx & 63, ks = (idx >> 6) & 3, nt = idx >> 8;
        int kbase = ks * 32 + ((l >> 4) << 3);
        int col = nt * 16 + (l & 15);
        bf16x8 r;
        #pragma unroll
        for (int i = 0; i < 8; ++i)
            r[i] = (short)f2bf(W1[(size_t)(kbase + i) * HID + col]);
        *reinterpret_cast<bf16x8*>(fragW + (size_t)idx * 8) = r;
    } else if (idx < 4096 + HID) {
        int n = idx - 4096;
        bw[n] = make_float2(b1[n], W2[n]);
    }
}

// ---- scan phase 1: per-block sums of deg_in ----
__global__ void k_scan1(const int* __restrict__ deg_in, int* __restrict__ partial) {
    __shared__ int sh[SCAN_BLK];
    int i = blockIdx.x * SCAN_BLK + threadIdx.x;
    int v = (i < NN) ? deg_in[i] : 0;
    sh[threadIdx.x] = v;
    __syncthreads();
    for (int off = SCAN_BLK / 2; off > 0; off >>= 1) {
        if (threadIdx.x < off) sh[threadIdx.x] += sh[threadIdx.x + off];
        __syncthreads();
    }
    if (threadIdx.x == 0) partial[blockIdx.x] = sh[0];
}

// ---- scan phase 2: wave-parallel exclusive scan of 391 partials ----
__global__ void k_scan2(int* __restrict__ partial) {
    int lane = threadIdx.x;   // 64 threads, 1 block
    int carry = 0;
    for (int c = 0; c < NSCAN; c += 64) {
        int idx = c + lane;
        int v = (idx < NSCAN) ? partial[idx] : 0;
        int s = v;
        #pragma unroll
        for (int off = 1; off < 64; off <<= 1) {
            int t = __shfl_up(s, off, 64);
            if (lane >= off) s += t;
        }
        if (idx < NSCAN) partial[idx] = s - v + carry;
        carry += __shfl(s, 63, 64);
    }
}

// ---- scan phase 3: in-block exclusive scan + block offset -> offsets, cursor ----
__global__ void k_scan3(const int* __restrict__ deg_in, const int* __restrict__ partial,
                        int* __restrict__ offsets, int* __restrict__ cursor) {
    __shared__ int sh[SCAN_BLK];
    int i = blockIdx.x * SCAN_BLK + threadIdx.x;
    int v = (i < NN) ? deg_in[i] : 0;
    sh[threadIdx.x] = v;
    __syncthreads();
    for (int off = 1; off < SCAN_BLK; off <<= 1) {
        int t = (threadIdx.x >= off) ? sh[threadIdx.x - off] : 0;
        __syncthreads();
        sh[threadIdx.x] += t;
        __syncthreads();
    }
    int ex = sh[threadIdx.x] - v + partial[blockIdx.x];
    if (i < NN) {
        offsets[i] = ex;
        cursor[i] = ex;
    }
    if (i == 0) offsets[NN] = NE;
}

// ---- CSR fill, XCD-partitioned by dst range ----
// group g = blockIdx&7 handles dst in [g*FRNG, (g+1)*FRNG): its csr slice
// (~0.8 MB) and cursor slice (50 KB) stay resident in one XCD's L2
// (blockIdx%8 -> XCD round-robin heuristic; correctness mapping-independent).
__global__ void k_fill(const int* __restrict__ src, const int* __restrict__ dst,
                       int* __restrict__ cursor, int* __restrict__ csr_src) {
    const int g = blockIdx.x & (FGRP - 1);
    const int vb = blockIdx.x >> 3;
    const int lo = g * FRNG, hiR = lo + FRNG;
    const int base = vb * EPB + threadIdx.x;
    #pragma unroll
    for (int k = 0; k < EPB / 256; ++k) {
        int e = base + k * 256;
        if (e < NE) {
            int d = dst[e];
            if (d >= lo && d < hiR) {
                int p = atomicAdd(&cursor[d], 1);
                csr_src[p] = src[e];
            }
        }
    }
}

// ---- gather: aggb[v] = bf16( nrm_in[v] * sum xs[src] ), one wave per row ----
__global__ void k_gather(const unsigned int* __restrict__ xs, const int* __restrict__ offsets,
                         const int* __restrict__ csr_src, const float* __restrict__ nrm_in,
                         unsigned int* __restrict__ aggb) {
    int row = blockIdx.x * 4 + (threadIdx.x >> 6);   // 4 waves/block
    if (row >= NN) return;
    int lane = threadIdx.x & 63;
    int beg = offsets[row], end = offsets[row + 1];
    float a0 = 0.f, a1 = 0.f, b0 = 0.f, b1 = 0.f;
    int j = beg;
    for (; j + 1 < end; j += 2) {
        unsigned int p0 = xs[(size_t)csr_src[j] * 64 + lane];
        unsigned int p1 = xs[(size_t)csr_src[j + 1] * 64 + lane];
        a0 += __uint_as_float(p0 << 16);
        a1 += __uint_as_float(p0 & 0xFFFF0000u);
        b0 += __uint_as_float(p1 << 16);
        b1 += __uint_as_float(p1 & 0xFFFF0000u);
    }
    if (j < end) {
        unsigned int p0 = xs[(size_t)csr_src[j] * 64 + lane];
        a0 += __uint_as_float(p0 << 16);
        a1 += __uint_as_float(p0 & 0xFFFF0000u);
    }
    float ni = nrm_in[row];
    float lo = (a0 + b0) * ni, hi = (a1 + b1) * ni;
    aggb[(size_t)row * 64 + lane] = f2bf(lo) | (f2bf(hi) << 16);
}

// ---- MFMA GEMM (no LDS) + relu + W2-dot + shfl-reduce -> z ----
__launch_bounds__(256)
__global__ void k_gemm(const unsigned short* __restrict__ aggb,
                       const unsigned short* __restrict__ fragW,
                       const float2* __restrict__ bw, const float* __restrict__ nrm_out,
                       float* __restrict__ z) {
    const int l = threadIdx.x & 63;
    const int w = threadIdx.x >> 6;
    const int r0 = blockIdx.x * 64 + w * 16;
    const int n15 = l & 15;
    const int hi = l >> 4;
    const int arow = r0 + n15;

    bf16x8 a[4];
    if (arow < NN) {
        #pragma unroll
        for (int ks = 0; ks < 4; ++ks)
            a[ks] = *reinterpret_cast<const bf16x8*>(aggb + (size_t)arow * INF + ks * 32 + (hi << 3));
    } else {
        #pragma unroll
        for (int ks = 0; ks < 4; ++ks) a[ks] = (bf16x8){0, 0, 0, 0, 0, 0, 0, 0};
    }

    float pacc[4] = {0.f, 0.f, 0.f, 0.f};
    #pragma unroll
    for (int nt = 0; nt < 16; ++nt) {
        f32x4 acc = {0.f, 0.f, 0.f, 0.f};
        #pragma unroll
        for (int ks = 0; ks < 4; ++ks) {
            bf16x8 b = *reinterpret_cast<const bf16x8*>(fragW + (size_t)(((nt * 4 + ks) * 64 + l) << 3));
            acc = __builtin_amdgcn_mfma_f32_16x16x32_bf16(a[ks], b, acc, 0, 0, 0);
        }
        float2 c = bw[nt * 16 + n15];
        #pragma unroll
        for (int g = 0; g < 4; ++g)
            pacc[g] += fmaxf(acc[g] + c.x, 0.f) * c.y;
    }
    #pragma unroll
    for (int off = 1; off < 16; off <<= 1) {
        #pragma unroll
        for (int g = 0; g < 4; ++g) pacc[g] += __shfl_xor(pacc[g], off, 64);
    }
    if (n15 == 0) {
        #pragma unroll
        for (int g = 0; g < 4; ++g) {
            int gr = r0 + (hi << 2) + g;
            if (gr < NN) z[gr] = nrm_out[gr] * pacc[g];
        }
    }
}

// ---- layer-2 gather + sigmoid: 16 lanes per node, shfl reduce ----
__global__ void k_out(const float* __restrict__ z, const int* __restrict__ offsets,
                      const int* __restrict__ csr_src, const float* __restrict__ nrm_in,
                      const float* __restrict__ b2, float* __restrict__ out) {
    int v = blockIdx.x * 16 + (threadIdx.x >> 4);
    if (v >= NN) return;
    int li = threadIdx.x & 15;
    int beg = offsets[v], end = offsets[v + 1];
    float s = 0.f;
    for (int j = beg + li; j < end; j += 16) s += z[csr_src[j]];
    #pragma unroll
    for (int off = 1; off < 16; off <<= 1) s += __shfl_xor(s, off, 64);
    if (li == 0) {
        float val = s * nrm_in[v] + b2[0];
        out[v] = 1.0f / (1.0f + expf(-val));
    }
}

extern "C" void kernel_launch(void* const* d_in, const int* in_sizes, int n_in,
                              void* d_out, int out_size, void* d_ws, size_t ws_size,
                              hipStream_t stream) {
    const float* x   = (const float*)d_in[0];
    const int*   src = (const int*)d_in[1];
    const int*   dst = (const int*)d_in[2];
    const float* W1  = (const float*)d_in[3];
    const float* b1  = (const float*)d_in[4];
    const float* W2  = (const float*)d_in[5];
    const float* b2  = (const float*)d_in[6];
    float* out = (float*)d_out;

    // workspace layout (cursor aliases deg_out; deg_out consumed by k_norms
    // before k_scan3 overwrites the region as cursor)
    int*   deg_out = (int*)d_ws;                     // NN
    int*   deg_in  = deg_out + NN;                   // NN
    int*   offsets = deg_in + NN;                    // NN+1
    int*   partial = offsets + NN + 1;               // NSCAN
    int*   csr_src = partial + NSCAN;                // NE
    float* nrm_out = (float*)(csr_src + NE);         // NN
    float* nrm_in  = nrm_out + NN;                   // NN
    float* z       = nrm_in + NN;                    // NN
    float2* bw     = (float2*)(z + NN);              // HID
    unsigned int* xs   = (unsigned int*)(bw + HID);  // NN*64  (25.6 MB)
    unsigned int* aggb = xs + (size_t)NN * 64;       // NN*64  (25.6 MB)
    unsigned short* fragW = (unsigned short*)(aggb + (size_t)NN * 64);  // 64 KB
    int* cursor = deg_out;

    (void)hipMemsetAsync(deg_out, 0, 2 * NN * sizeof(int), stream);

    k_wfrag<<<17, 256, 0, stream>>>(W1, b1, W2, fragW, bw);
    k_count<<<(NE + 255) / 256, 256, 0, stream>>>(src, dst, deg_out, deg_in);
    k_norms<<<(NN + 255) / 256, 256, 0, stream>>>(deg_out, deg_in, nrm_out, nrm_in);
    k_xconv<<<(NN * 64 + 255) / 256, 256, 0, stream>>>(x, nrm_out, xs);
    k_scan1<<<NSCAN, SCAN_BLK, 0, stream>>>(deg_in, partial);
    k_scan2<<<1, 64, 0, stream>>>(partial);
    k_scan3<<<NSCAN, SCAN_BLK, 0, stream>>>(deg_in, partial, offsets, cursor);
    k_fill<<<NVB * FGRP, 256, 0, stream>>>(src, dst, cursor, csr_src);
    k_gather<<<NN / 4, 256, 0, stream>>>(xs, offsets, csr_src, nrm_in, aggb);
    k_gemm<<<(NN + 63) / 64, 256, 0, stream>>>((const unsigned short*)aggb, fragW, bw, nrm_out, z);
    k_out<<<(NN + 15) / 16, 256, 0, stream>>>(z, offsets, csr_src, nrm_in, b2, out);
}